// Round 7
// baseline (364.736 us; speedup 1.0000x reference)
//
#include <hip/hip_runtime.h>

#define NEG_INF_VAL -1000000.0f

typedef short s16x8 __attribute__((ext_vector_type(8)));
typedef float f32x4 __attribute__((ext_vector_type(4)));

__device__ __forceinline__ unsigned int bf16_rne(float f) {
  unsigned int u = __float_as_uint(f);
  return (u + 0x7fffu + ((u >> 16) & 1u)) >> 16;
}
__device__ __forceinline__ unsigned int pack_bf2(float a, float b) {
  return bf16_rne(a) | (bf16_rne(b) << 16);
}

// tanh(x) = 1 - 2/(e^2x + 1); saturates correctly for |x| large (exp->0/inf).
__device__ __forceinline__ float fast_tanh(float x) {
  float t = __expf(2.f * x);
  return 1.f - __fdividef(2.f, t + 1.f);
}

// ---------------- K1: fp32 -> bf16 convert (vectorized, grid-stride) ---------
__global__ __launch_bounds__(256) void convert_bf16_kernel(
    const float* __restrict__ src, unsigned short* __restrict__ dst, long n) {
  long i = ((long)blockIdx.x * blockDim.x + threadIdx.x) * 8;
  long stride = (long)gridDim.x * blockDim.x * 8;
  for (; i < n; i += stride) {
    float4 f0 = *(const float4*)(src + i);
    float4 f1 = *(const float4*)(src + i + 4);
    uint4 o;
    o.x = pack_bf2(f0.x, f0.y);
    o.y = pack_bf2(f0.z, f0.w);
    o.z = pack_bf2(f1.x, f1.y);
    o.w = pack_bf2(f1.z, f1.w);
    *(uint4*)(dst + i) = o;
  }
}

// ---------------- K2: targetT[b,d] = sum_q input[b,q] * W_q[d,q] -------------
__global__ __launch_bounds__(256) void targetT_kernel(
    const float* __restrict__ input, const float* __restrict__ Wq,
    float* __restrict__ tT) {
  int d0 = blockIdx.x * 8;
  int t = threadIdx.x;
  int b = t >> 3, dl = t & 7;
  __shared__ float in_s[32][32];
  __shared__ float wq_s[8][32];
  float acc = 0.f;
  for (int q0 = 0; q0 < 1024; q0 += 32) {
    int r = t >> 3, c = (t & 7) * 4;
    *(float4*)&in_s[r][c] = *(const float4*)&input[r * 1024 + q0 + c];
    wq_s[t >> 5][t & 31] = Wq[(long)(d0 + (t >> 5)) * 1024 + q0 + (t & 31)];
    __syncthreads();
#pragma unroll
    for (int qq = 0; qq < 32; ++qq)
      acc += in_s[b][qq] * wq_s[dl][qq];
    __syncthreads();
  }
  tT[b * 1024 + d0 + dl] = acc;
}

// ---------------- K3: big GEMM + fused bias/tanh/energy-partial epilogue -----
// C[m,d] = sum_a ctx_bf16[m,a] * Wpre_bf16[d,a]  (NT GEMM)
// 128x128 tile, BK=32, 4 waves (2x2, 64x64/wave), m97-style simple loop.
// __launch_bounds__(256,4): total regs <=128 (acc 64 + frags 32 + addr ~20)
// -> 4 waves/SIMD -> 4 co-resident blocks/CU (LDS 16 KB). Block-level TLP
// hides the per-iter vmcnt(0) drain, prologue, and the VALU-heavy epilogue.
__device__ __forceinline__ void load_lds16(const void* g, void* l) {
  __builtin_amdgcn_global_load_lds(
      (const __attribute__((address_space(1))) void*)g,
      (__attribute__((address_space(3))) void*)l, 16, 0, 0);
}

__global__ __launch_bounds__(256, 4) void gemm_energy_kernel(
    const unsigned short* __restrict__ A,   // [65536][1024] bf16
    const unsigned short* __restrict__ B,   // [1024][1024] bf16 (W_pre, N x K)
    const float* __restrict__ b_pre,        // [1024]
    const float* __restrict__ tT,           // [32][1024]
    const float* __restrict__ vvec,         // [1024]
    float* __restrict__ Cout,               // precompute [65536][1024] fp32
    float* __restrict__ epart) {            // [65536][16] fp32 partial energies
  const int K = 1024;
  const int N = 1024;
  // XCD-aware bijective swizzle: XCD x gets mt-band [x*64, x*64+64), nt fastest.
  int lin = blockIdx.x;                    // 0..4095, xcd = lin % 8
  int w = (lin & 7) * 512 + (lin >> 3);
  int nt = w & 7;                          // 0..7
  int mt = w >> 3;                         // 0..511
  int m0 = mt * 128, n0 = nt * 128;
  int tid = threadIdx.x;
  int lane = tid & 63, wid = tid >> 6;
  int wr = wid >> 1, wc = wid & 1;

  __shared__ unsigned short sA[128][32];
  __shared__ unsigned short sB[128][32];

  f32x4 acc[4][4] = {};

  // staging: lane l -> LDS offset l*16 (linear). row = l>>2, lds_slot = l&3.
  // content must be global slot (l&3) ^ swz(row), swz(row) = (row>>1)&3 = (l>>3)&3
  int srow = lane >> 2;
  int scol = ((lane & 3) ^ ((lane >> 3) & 3)) * 8;
  const unsigned short* Ag = A + (long)(m0 + wid * 32 + srow) * K + scol;
  const unsigned short* Bg = B + (long)(n0 + wid * 32 + srow) * K + scol;
  unsigned short* sA0 = &sA[wid * 32][0];
  unsigned short* sA1 = &sA[wid * 32 + 16][0];
  unsigned short* sB0 = &sB[wid * 32][0];
  unsigned short* sB1 = &sB[wid * 32 + 16][0];

  int r = lane & 15, g = lane >> 4;
  int slotA = (g ^ ((r >> 1) & 3)) * 8;    // read-side swizzle

  for (int k0 = 0; k0 < K; k0 += 32) {
    load_lds16(Ag, sA0);
    load_lds16(Ag + 16 * K, sA1);
    load_lds16(Bg, sB0);
    load_lds16(Bg + 16 * K, sB1);
    Ag += 32; Bg += 32;
    asm volatile("s_waitcnt vmcnt(0)" ::: "memory");
    __syncthreads();
    s16x8 af[4], bfr[4];
#pragma unroll
    for (int i = 0; i < 4; ++i)
      af[i] = *(const s16x8*)&sA[wr * 64 + i * 16 + r][slotA];
#pragma unroll
    for (int j = 0; j < 4; ++j)
      bfr[j] = *(const s16x8*)&sB[wc * 64 + j * 16 + r][slotA];
    __builtin_amdgcn_s_setprio(1);
#pragma unroll
    for (int i = 0; i < 4; ++i)
#pragma unroll
      for (int j = 0; j < 4; ++j)
        acc[i][j] = __builtin_amdgcn_mfma_f32_16x16x32_bf16(af[i], bfr[j], acc[i][j], 0, 0, 0);
    __builtin_amdgcn_s_setprio(0);
    __syncthreads();
  }

  // Epilogue: C = acc + b_pre; energy partial = sum_d tanh(C + tT) * v
  int b = m0 >> 11;  // 128 | 2048 -> batch uniform per block
  float bp[4], tv[4], vv[4];
#pragma unroll
  for (int j = 0; j < 4; ++j) {
    int d = n0 + wc * 64 + j * 16 + r;
    bp[j] = b_pre[d];
    tv[j] = tT[b * 1024 + d];
    vv[j] = vvec[d];
  }
#pragma unroll
  for (int i = 0; i < 4; ++i) {
#pragma unroll
    for (int q = 0; q < 4; ++q) {
      int m = m0 + wr * 64 + i * 16 + g * 4 + q;
      float e = 0.f;
#pragma unroll
      for (int j = 0; j < 4; ++j) {
        float val = acc[i][j][q] + bp[j];
        Cout[(long)m * N + n0 + wc * 64 + j * 16 + r] = val;
        e += fast_tanh(val + tv[j]) * vv[j];
      }
      // reduce across the 16 lanes holding this row's columns
      e += __shfl_xor(e, 1);
      e += __shfl_xor(e, 2);
      e += __shfl_xor(e, 4);
      e += __shfl_xor(e, 8);
      if (r == 0) epart[(long)m * 16 + nt * 2 + wc] = e;
    }
  }
}

// ---------------- K4: reduce partials, mask, softmax over S ------------------
__global__ __launch_bounds__(256) void softmax_kernel(
    const float* __restrict__ epart, const int* __restrict__ mask,
    float* __restrict__ score) {
  int b = blockIdx.x;
  int t = threadIdx.x;
  __shared__ float red[256];
  float ev[8];
  float mx = -3.4e38f;
#pragma unroll
  for (int ii = 0; ii < 8; ++ii) {
    int s = ii * 256 + t;
    long m = (long)b * 2048 + s;
    const float4* p = (const float4*)(epart + m * 16);
    float4 p0 = p[0], p1 = p[1], p2 = p[2], p3 = p[3];
    float e = p0.x + p0.y + p0.z + p0.w + p1.x + p1.y + p1.z + p1.w
            + p2.x + p2.y + p2.z + p2.w + p3.x + p3.y + p3.z + p3.w;
    if (mask[b * 2048 + s] == 0) e = NEG_INF_VAL;
    ev[ii] = e;
    mx = fmaxf(mx, e);
  }
  red[t] = mx; __syncthreads();
  for (int off = 128; off > 0; off >>= 1) {
    if (t < off) red[t] = fmaxf(red[t], red[t + off]);
    __syncthreads();
  }
  mx = red[0];
  __syncthreads();
  float sum = 0.f;
#pragma unroll
  for (int ii = 0; ii < 8; ++ii) { ev[ii] = __expf(ev[ii] - mx); sum += ev[ii]; }
  red[t] = sum; __syncthreads();
  for (int off = 128; off > 0; off >>= 1) {
    if (t < off) red[t] += red[t + off];
    __syncthreads();
  }
  float inv = 1.f / red[0];
#pragma unroll
  for (int ii = 0; ii < 8; ++ii)
    score[b * 2048 + ii * 256 + t] = ev[ii] * inv;
}

// ---------------- K5: weightedContext partials over s-chunks -----------------
__global__ __launch_bounds__(256) void wc_partial_kernel(
    const unsigned short* __restrict__ ctx, const float* __restrict__ score,
    float* __restrict__ part) {
  int b = blockIdx.x, sc = blockIdx.y;
  int t = threadIdx.x;
  __shared__ float ssc[64];
  if (t < 64) ssc[t] = score[b * 2048 + sc * 64 + t];
  __syncthreads();
  float acc0 = 0.f, acc1 = 0.f, acc2 = 0.f, acc3 = 0.f;
  const unsigned short* cp = ctx + ((long)b * 2048 + sc * 64) * 1024 + t * 4;
  for (int s = 0; s < 64; ++s) {
    uint2 pk = *(const uint2*)cp;
    cp += 1024;
    float wgt = ssc[s];
    acc0 += wgt * __uint_as_float(pk.x << 16);
    acc1 += wgt * __uint_as_float(pk.x & 0xffff0000u);
    acc2 += wgt * __uint_as_float(pk.y << 16);
    acc3 += wgt * __uint_as_float(pk.y & 0xffff0000u);
  }
  float* pp = part + ((long)(b * 32 + sc)) * 1024 + t * 4;
  pp[0] = acc0; pp[1] = acc1; pp[2] = acc2; pp[3] = acc3;
}

// ---------------- K6: reduce wc partials -------------------------------------
__global__ __launch_bounds__(256) void wc_reduce_kernel(
    const float* __restrict__ part, float* __restrict__ wc) {
  int id = blockIdx.x * 256 + threadIdx.x;  // 0..32767
  int b = id >> 10, a = id & 1023;
  float s = 0.f;
#pragma unroll
  for (int scn = 0; scn < 32; ++scn)
    s += part[((long)(b * 32 + scn)) * 1024 + a];
  wc[id] = s;
}

extern "C" void kernel_launch(void* const* d_in, const int* in_sizes, int n_in,
                              void* d_out, int out_size, void* d_ws, size_t ws_size,
                              hipStream_t stream) {
  const float* input   = (const float*)d_in[0];  // 32*1024
  const float* context = (const float*)d_in[1];  // 32*2048*1024
  const float* W_pre   = (const float*)d_in[2];  // 1024*1024
  const float* b_pre   = (const float*)d_in[3];  // 1024
  const float* W_q     = (const float*)d_in[4];  // 1024*1024
  const float* v       = (const float*)d_in[5];  // 1024
  const int*   mask    = (const int*)d_in[6];    // 32*2048

  float* out       = (float*)d_out;
  float* out_wc    = out;                  // 32*1024
  float* out_score = out + 32768;          // 32*2048
  float* out_pre   = out + 98304;          // 32*2048*1024

  // workspace layout (bytes)
  const size_t OFF_CTX   = 0;           // 64M bf16 = 134217728
  const size_t OFF_WPRE  = 134217728;   // 1M bf16  = 2097152
  const size_t OFF_TT    = 136314880;   // 32768 f32 = 131072
  const size_t OFF_EPART = 136445952;   // 65536*16 f32 = 4194304
  const size_t OFF_WCP   = 140640256;   // 32*32*1024 f32 = 4194304
  const size_t WS_NEED   = 144834560;
  if (ws_size < WS_NEED) return;  // fail visibly rather than corrupt

  char* ws = (char*)d_ws;
  unsigned short* ctx_bf  = (unsigned short*)(ws + OFF_CTX);
  unsigned short* wpre_bf = (unsigned short*)(ws + OFF_WPRE);
  float* tT     = (float*)(ws + OFF_TT);
  float* epart  = (float*)(ws + OFF_EPART);
  float* wcpart = (float*)(ws + OFF_WCP);

  convert_bf16_kernel<<<2048, 256, 0, stream>>>(context, ctx_bf, 64LL * 1024 * 1024);
  convert_bf16_kernel<<<256, 256, 0, stream>>>(W_pre, wpre_bf, 1024LL * 1024);
  targetT_kernel<<<128, 256, 0, stream>>>(input, W_q, tT);
  gemm_energy_kernel<<<4096, 256, 0, stream>>>(ctx_bf, wpre_bf, b_pre, tT, v,
                                               out_pre, epart);
  softmax_kernel<<<32, 256, 0, stream>>>(epart, mask, out_score);
  dim3 g5(32, 32);
  wc_partial_kernel<<<g5, 256, 0, stream>>>(ctx_bf, out_score, wcpart);
  wc_reduce_kernel<<<128, 256, 0, stream>>>(wcpart, out_wc);
}

// Round 8
// 337.961 us; speedup vs baseline: 1.0792x; 1.0792x over previous
//
#include <hip/hip_runtime.h>

#define NEG_INF_VAL -1000000.0f

typedef short s16x8 __attribute__((ext_vector_type(8)));
typedef float f32x4 __attribute__((ext_vector_type(4)));

__device__ __forceinline__ unsigned int bf16_rne(float f) {
  unsigned int u = __float_as_uint(f);
  return (u + 0x7fffu + ((u >> 16) & 1u)) >> 16;
}
__device__ __forceinline__ unsigned int pack_bf2(float a, float b) {
  return bf16_rne(a) | (bf16_rne(b) << 16);
}

// tanh(x) = 1 - 2/(e^2x + 1); saturates correctly for |x| large.
__device__ __forceinline__ float fast_tanh(float x) {
  float t = __expf(2.f * x);
  return 1.f - __fdividef(2.f, t + 1.f);
}

// ---------------- K1: fp32 -> bf16 convert (vectorized, grid-stride) ---------
__global__ __launch_bounds__(256) void convert_bf16_kernel(
    const float* __restrict__ src, unsigned short* __restrict__ dst, long n) {
  long i = ((long)blockIdx.x * blockDim.x + threadIdx.x) * 8;
  long stride = (long)gridDim.x * blockDim.x * 8;
  for (; i < n; i += stride) {
    float4 f0 = *(const float4*)(src + i);
    float4 f1 = *(const float4*)(src + i + 4);
    uint4 o;
    o.x = pack_bf2(f0.x, f0.y);
    o.y = pack_bf2(f0.z, f0.w);
    o.z = pack_bf2(f1.x, f1.y);
    o.w = pack_bf2(f1.z, f1.w);
    *(uint4*)(dst + i) = o;
  }
}

// ---------------- K2: targetT[b,d] = sum_q input[b,q] * W_q[d,q] -------------
__global__ __launch_bounds__(256) void targetT_kernel(
    const float* __restrict__ input, const float* __restrict__ Wq,
    float* __restrict__ tT) {
  int d0 = blockIdx.x * 8;
  int t = threadIdx.x;
  int b = t >> 3, dl = t & 7;
  __shared__ float in_s[32][32];
  __shared__ float wq_s[8][32];
  float acc = 0.f;
  for (int q0 = 0; q0 < 1024; q0 += 32) {
    int r = t >> 3, c = (t & 7) * 4;
    *(float4*)&in_s[r][c] = *(const float4*)&input[r * 1024 + q0 + c];
    wq_s[t >> 5][t & 31] = Wq[(long)(d0 + (t >> 5)) * 1024 + q0 + (t & 31)];
    __syncthreads();
#pragma unroll
    for (int qq = 0; qq < 32; ++qq)
      acc += in_s[b][qq] * wq_s[dl][qq];
    __syncthreads();
  }
  tT[b * 1024 + d0 + dl] = acc;
}

// ---------------- K3: big GEMM + fused bias/tanh/energy-partial epilogue -----
// C[m,d] = sum_a ctx_bf16[m,a] * Wpre_bf16[d,a]  (NT GEMM)
// 256x256 tile, BK=64, 8 waves (2Mx4N), m201 8-phase template with BARE
// counted waits (no "memory" clobbers -> compiler keeps counted vmcnt and
// inserts fine-grained lgkmcnt per fragment use). vmcnt(4) at P4/P8 only:
// every staged granule completes >=3 phases before its first read.
__device__ __forceinline__ void load_lds16(const void* g, void* l) {
  __builtin_amdgcn_global_load_lds(
      (const __attribute__((address_space(1))) void*)g,
      (__attribute__((address_space(3))) void*)l, 16, 0, 0);
}

#define MFMA_ROW(QI, I, AF)                                                          \
  acc[(QI)*4+(I)][0] = __builtin_amdgcn_mfma_f32_16x16x32_bf16(AF, bf0, acc[(QI)*4+(I)][0], 0, 0, 0); \
  acc[(QI)*4+(I)][1] = __builtin_amdgcn_mfma_f32_16x16x32_bf16(AF, bf1, acc[(QI)*4+(I)][1], 0, 0, 0); \
  acc[(QI)*4+(I)][2] = __builtin_amdgcn_mfma_f32_16x16x32_bf16(AF, bf2, acc[(QI)*4+(I)][2], 0, 0, 0); \
  acc[(QI)*4+(I)][3] = __builtin_amdgcn_mfma_f32_16x16x32_bf16(AF, bf3, acc[(QI)*4+(I)][3], 0, 0, 0);

// Stage one half-tile (SB,SM,SK literals; SKT = K-tile relative to Ag/Bg).
#define STAGE(SB, SM, SK, SKT)                                                       \
  {                                                                                  \
    const unsigned short* gp = ((SM) ? Bg : Ag) + (SKT) * 64 + (SK) * 32;            \
    char* lp = dstB + (SB) * 65536 + (SM) * 32768 + (SK) * 16384;                    \
    load_lds16(gp, lp);                                                              \
    load_lds16(gp + 128L * 1024, lp + 8192);                                         \
  }

// One phase: {ds_read frags | stage 1 half-tile | 16 MFMA | [vmcnt(4)] | bar}
#define PHASE(BUF, QI, KK, LOADB, SB, SM, SK, SKT, VM)                               \
  {                                                                                  \
    const unsigned short* pA = (BUF) ? pA1 : pA0;                                    \
    s16x8 af0 = *(const s16x8*)(pA + (KK)*8192 + ((QI)*64 +  0)*32);                 \
    s16x8 af1 = *(const s16x8*)(pA + (KK)*8192 + ((QI)*64 + 16)*32);                 \
    s16x8 af2 = *(const s16x8*)(pA + (KK)*8192 + ((QI)*64 + 32)*32);                 \
    s16x8 af3 = *(const s16x8*)(pA + (KK)*8192 + ((QI)*64 + 48)*32);                 \
    if (LOADB) {                                                                     \
      const unsigned short* pB = (BUF) ? pB1 : pB0;                                  \
      bf0 = *(const s16x8*)(pB + (KK)*8192 +  0*32);                                 \
      bf1 = *(const s16x8*)(pB + (KK)*8192 + 16*32);                                 \
      bf2 = *(const s16x8*)(pB + (KK)*8192 + 32*32);                                 \
      bf3 = *(const s16x8*)(pB + (KK)*8192 + 48*32);                                 \
    }                                                                                \
    STAGE(SB, SM, SK, SKT)                                                           \
    __builtin_amdgcn_s_setprio(1);                                                   \
    MFMA_ROW(QI, 0, af0)                                                             \
    MFMA_ROW(QI, 1, af1)                                                             \
    MFMA_ROW(QI, 2, af2)                                                             \
    MFMA_ROW(QI, 3, af3)                                                             \
    __builtin_amdgcn_s_setprio(0);                                                   \
    if (VM) {                                                                        \
      asm volatile("s_waitcnt vmcnt(4)");                                            \
      __builtin_amdgcn_sched_barrier(0);                                             \
    }                                                                                \
    __builtin_amdgcn_s_barrier();                                                    \
  }

__global__ __launch_bounds__(512, 2) void gemm_energy_kernel(
    const unsigned short* __restrict__ A,   // [65536][1024] bf16
    const unsigned short* __restrict__ Bm,  // [1024][1024] bf16 (W_pre, N x K)
    const float* __restrict__ b_pre,        // [1024]
    const float* __restrict__ tT,           // [32][1024]
    const float* __restrict__ vvec,         // [1024]
    float* __restrict__ Cout,               // precompute [65536][1024] fp32
    float* __restrict__ epart) {            // [65536][16] fp32 partial energies
  // XCD-aware swizzle: nwg=1024 (%8==0); nt fastest within an XCD chunk.
  int lin = blockIdx.x;
  int w = (lin & 7) * 128 + (lin >> 3);
  int nt = w & 3;
  int mt = w >> 2;
  int m0 = mt * 256, n0 = nt * 256;
  int tid = threadIdx.x;
  int lane = tid & 63, wid = tid >> 6;     // 8 waves
  int wr = wid >> 2, wc = wid & 3;         // 2 x 4
  int r = lane & 15, g = lane >> 4;

  // flat LDS: [buf][mat][kk][256 rows][32 cols] bf16 = 128 KiB
  // element strides: buf 32768, mat 16384, kk 8192
  __shared__ unsigned short sMem[2 * 2 * 2 * 256 * 32];

  f32x4 acc[8][4] = {};
  s16x8 bf0, bf1, bf2, bf3;

  // read-side swizzled 16B slot (element offset): phys = g ^ ((r>>1)&3)
  int physoff = (g ^ ((r >> 1) & 3)) * 8;

  // 4 runtime LDS read bases; all per-phase offsets are compile-time imms.
  int aoffe = (wr * 128 + r) * 32 + physoff;
  int boffe = (wc * 64 + r) * 32 + physoff;
  const unsigned short* pA0 = sMem + aoffe;
  const unsigned short* pA1 = sMem + 32768 + aoffe;
  const unsigned short* pB0 = sMem + 16384 + boffe;
  const unsigned short* pB1 = sMem + 49152 + boffe;
  char* dstB = (char*)sMem + wid * 1024;   // linear gload_lds dest slice

  // staging source: thread covers rows {tid>>2, tid>>2+128}; global col
  // pre-swizzled: physical slot (tid&3) holds logical (tid&3)^((tid>>3)&3).
  // NOTE: tail prefetch over-reads past each matrix end; lands in the
  // adjacent workspace region (ctx_bf->wpre_bf->tT), harmless & in-bounds.
  int srow = tid >> 2;
  int slog8 = ((tid & 3) ^ ((tid >> 3) & 3)) * 8;
  const unsigned short* Abase = A + (long)(m0 + srow) * 1024 + slog8;
  const unsigned short* Bbase = Bm + (long)(n0 + srow) * 1024 + slog8;
  const unsigned short* Ag = Abase;
  const unsigned short* Bg = Bbase;

  // ---- prologue: buf0 = tile 0 (4 half-tiles), buf1.kk0 = tile 1 ----
  STAGE(0, 0, 0, 0) STAGE(0, 1, 0, 0)
  STAGE(0, 0, 1, 0) STAGE(0, 1, 1, 0)
  STAGE(1, 0, 0, 1) STAGE(1, 1, 0, 1)
  asm volatile("s_waitcnt vmcnt(4)");      // tile 0 (8 oldest loads) landed
  __builtin_amdgcn_sched_barrier(0);
  __builtin_amdgcn_s_barrier();

  // ---- main loop: 8 iters x 2 K-tiles, 8 phases, 1 barrier/phase ----
#pragma unroll 1
  for (int t0 = 0; t0 < 16; t0 += 2) {
    Ag = Abase + t0 * 64;
    Bg = Bbase + t0 * 64;
    //    BUF QI KK LOADB  SB SM SK SKT  VM
    PHASE(0, 0, 0, 1,     1, 0, 1, 1,   0)   // P1: stage buf1.A.kk1 (t0+1)
    PHASE(0, 1, 0, 0,     1, 1, 1, 1,   0)   // P2: stage buf1.B.kk1
    PHASE(0, 0, 1, 1,     0, 0, 0, 2,   0)   // P3: stage buf0.A.kk0 (t0+2)
    PHASE(0, 1, 1, 0,     0, 1, 0, 2,   1)   // P4: stage buf0.B.kk0  [vmcnt]
    PHASE(1, 0, 0, 1,     0, 0, 1, 2,   0)   // P5: stage buf0.A.kk1
    PHASE(1, 1, 0, 0,     0, 1, 1, 2,   0)   // P6: stage buf0.B.kk1
    PHASE(1, 0, 1, 1,     1, 0, 0, 3,   0)   // P7: stage buf1.A.kk0 (t0+3)
    PHASE(1, 1, 1, 0,     1, 1, 0, 3,   1)   // P8: stage buf1.B.kk0  [vmcnt]
  }
  // drain tail DMAs before LDS dealloc / block end
  asm volatile("s_waitcnt vmcnt(0)");

  // ---- epilogue: C = acc + b_pre; energy partial = sum_d tanh(C+tT)*v ----
  int b = m0 >> 11;  // 256 | 2048 -> batch uniform per block
  float bias[4], tv[4], vv[4];
#pragma unroll
  for (int j = 0; j < 4; ++j) {
    int d = n0 + wc * 64 + j * 16 + r;
    bias[j] = b_pre[d];
    tv[j] = tT[b * 1024 + d];
    vv[j] = vvec[d];
  }
#pragma unroll
  for (int i = 0; i < 8; ++i) {
#pragma unroll
    for (int q = 0; q < 4; ++q) {
      int m = m0 + wr * 128 + i * 16 + g * 4 + q;
      float e = 0.f;
#pragma unroll
      for (int j = 0; j < 4; ++j) {
        float val = acc[i][j][q] + bias[j];
        Cout[(long)m * 1024 + n0 + wc * 64 + j * 16 + r] = val;
        e += fast_tanh(val + tv[j]) * vv[j];
      }
      e += __shfl_xor(e, 1);
      e += __shfl_xor(e, 2);
      e += __shfl_xor(e, 4);
      e += __shfl_xor(e, 8);
      if (r == 0) epart[(long)m * 16 + nt * 4 + wc] = e;
    }
  }
}

// ---------------- K4: reduce partials, mask, softmax over S ------------------
__global__ __launch_bounds__(256) void softmax_kernel(
    const float* __restrict__ epart, const int* __restrict__ mask,
    float* __restrict__ score) {
  int b = blockIdx.x;
  int t = threadIdx.x;
  __shared__ float red[256];
  float ev[8];
  float mx = -3.4e38f;
#pragma unroll
  for (int ii = 0; ii < 8; ++ii) {
    int s = ii * 256 + t;
    long m = (long)b * 2048 + s;
    const float4* p = (const float4*)(epart + m * 16);
    float4 p0 = p[0], p1 = p[1], p2 = p[2], p3 = p[3];
    float e = p0.x + p0.y + p0.z + p0.w + p1.x + p1.y + p1.z + p1.w
            + p2.x + p2.y + p2.z + p2.w + p3.x + p3.y + p3.z + p3.w;
    if (mask[b * 2048 + s] == 0) e = NEG_INF_VAL;
    ev[ii] = e;
    mx = fmaxf(mx, e);
  }
  red[t] = mx; __syncthreads();
  for (int off = 128; off > 0; off >>= 1) {
    if (t < off) red[t] = fmaxf(red[t], red[t + off]);
    __syncthreads();
  }
  mx = red[0];
  __syncthreads();
  float sum = 0.f;
#pragma unroll
  for (int ii = 0; ii < 8; ++ii) { ev[ii] = __expf(ev[ii] - mx); sum += ev[ii]; }
  red[t] = sum; __syncthreads();
  for (int off = 128; off > 0; off >>= 1) {
    if (t < off) red[t] += red[t + off];
    __syncthreads();
  }
  float inv = 1.f / red[0];
#pragma unroll
  for (int ii = 0; ii < 8; ++ii)
    score[b * 2048 + ii * 256 + t] = ev[ii] * inv;
}

// ---------------- K5: weightedContext partials over s-chunks -----------------
__global__ __launch_bounds__(256) void wc_partial_kernel(
    const unsigned short* __restrict__ ctx, const float* __restrict__ score,
    float* __restrict__ part) {
  int b = blockIdx.x, sc = blockIdx.y;
  int t = threadIdx.x;
  __shared__ float ssc[64];
  if (t < 64) ssc[t] = score[b * 2048 + sc * 64 + t];
  __syncthreads();
  float acc0 = 0.f, acc1 = 0.f, acc2 = 0.f, acc3 = 0.f;
  const unsigned short* cp = ctx + ((long)b * 2048 + sc * 64) * 1024 + t * 4;
  for (int s = 0; s < 64; ++s) {
    uint2 pk = *(const uint2*)cp;
    cp += 1024;
    float wgt = ssc[s];
    acc0 += wgt * __uint_as_float(pk.x << 16);
    acc1 += wgt * __uint_as_float(pk.x & 0xffff0000u);
    acc2 += wgt * __uint_as_float(pk.y << 16);
    acc3 += wgt * __uint_as_float(pk.y & 0xffff0000u);
  }
  float* pp = part + ((long)(b * 32 + sc)) * 1024 + t * 4;
  pp[0] = acc0; pp[1] = acc1; pp[2] = acc2; pp[3] = acc3;
}

// ---------------- K6: reduce wc partials -------------------------------------
__global__ __launch_bounds__(256) void wc_reduce_kernel(
    const float* __restrict__ part, float* __restrict__ wc) {
  int id = blockIdx.x * 256 + threadIdx.x;  // 0..32767
  int b = id >> 10, a = id & 1023;
  float s = 0.f;
#pragma unroll
  for (int scn = 0; scn < 32; ++scn)
    s += part[((long)(b * 32 + scn)) * 1024 + a];
  wc[id] = s;
}

extern "C" void kernel_launch(void* const* d_in, const int* in_sizes, int n_in,
                              void* d_out, int out_size, void* d_ws, size_t ws_size,
                              hipStream_t stream) {
  const float* input   = (const float*)d_in[0];  // 32*1024
  const float* context = (const float*)d_in[1];  // 32*2048*1024
  const float* W_pre   = (const float*)d_in[2];  // 1024*1024
  const float* b_pre   = (const float*)d_in[3];  // 1024
  const float* W_q     = (const float*)d_in[4];  // 1024*1024
  const float* v       = (const float*)d_in[5];  // 1024
  const int*   mask    = (const int*)d_in[6];    // 32*2048

  float* out       = (float*)d_out;
  float* out_wc    = out;                  // 32*1024
  float* out_score = out + 32768;          // 32*2048
  float* out_pre   = out + 98304;          // 32*2048*1024

  // workspace layout (bytes)
  const size_t OFF_CTX   = 0;           // 64M bf16 = 134217728
  const size_t OFF_WPRE  = 134217728;   // 1M bf16  = 2097152
  const size_t OFF_TT    = 136314880;   // 32768 f32 = 131072
  const size_t OFF_EPART = 136445952;   // 65536*16 f32 = 4194304
  const size_t OFF_WCP   = 140640256;   // 32*32*1024 f32 = 4194304
  const size_t WS_NEED   = 144834560;
  if (ws_size < WS_NEED) return;  // fail visibly rather than corrupt

  char* ws = (char*)d_ws;
  unsigned short* ctx_bf  = (unsigned short*)(ws + OFF_CTX);
  unsigned short* wpre_bf = (unsigned short*)(ws + OFF_WPRE);
  float* tT     = (float*)(ws + OFF_TT);
  float* epart  = (float*)(ws + OFF_EPART);
  float* wcpart = (float*)(ws + OFF_WCP);

  convert_bf16_kernel<<<2048, 256, 0, stream>>>(context, ctx_bf, 64LL * 1024 * 1024);
  convert_bf16_kernel<<<256, 256, 0, stream>>>(W_pre, wpre_bf, 1024LL * 1024);
  targetT_kernel<<<128, 256, 0, stream>>>(input, W_q, tT);
  gemm_energy_kernel<<<1024, 512, 0, stream>>>(ctx_bf, wpre_bf, b_pre, tT, v,
                                               out_pre, epart);
  softmax_kernel<<<32, 256, 0, stream>>>(epart, mask, out_score);
  dim3 g5(32, 32);
  wc_partial_kernel<<<g5, 256, 0, stream>>>(ctx_bf, out_score, wcpart);
  wc_reduce_kernel<<<128, 256, 0, stream>>>(wcpart, out_wc);
}